// Round 2
// baseline (148.658 us; speedup 1.0000x reference)
//
#include <hip/hip_runtime.h>

// ISTFT via batched real-IFFT (radix-4, in-place LDS) + in-LDS overlap-add.
//
// Identity: reference einsum with W_real/W_imag == win ⊙ IDFT_2048(hermitian
// extension); Im F[0], Im F[1024] multiply zero sin-columns (dropped).
// Per frame (n=2048, m=1024):
//   1) real-IFFT pack (k=0..1023), 1/m normalization folded in:
//      Z[k] = [ (X[k]+conj(X[m-k])) + i e^{+2πik/n}(X[k]-conj(X[m-k])) ]*0.5/m
//   2) 1024-pt complex inverse FFT: radix-4 DIT, base-4-digit-reversed input,
//      e^{+} twiddles, 5 stages, IN-PLACE single LDS buffer (stages 0-3 are
//      wave-local -> wave_barrier only; 2 hw barriers per frame + 1 for OA).
//   3) x[2p]=Re z[p], x[2p+1]=Im z[p]; windowed samples accumulate into LDS OA.
//
// R10 vs R9 (theory: R9 showed barriers/norm were NOT the cost; the S bf16
// intermediate round-trip was): each block owns 8 CONSECUTIVE frames of one
// batch (125 blocks x 8 frames = 1000 exactly -> ZERO recompute). Overlap-add
// happens in a 5632-float LDS window. Middle 2560 outputs/block are complete
// in-block (wss == 1.5 exactly there) -> stored directly. The 1536-sample
// seams are stored as fp32 partials to scratch (12.3 MB); a tiny seam kernel
// sums the two partials per boundary and normalizes (generic wss only for the
// global edges n<1536 / n>=512000). Kills: S workspace (65.6 MB round-trip),
// the norm kernel, and the bf16 quantization (absmax should drop ~20x).

#define N_FFT    2048
#define HOP      512
#define T_FRAMES 1000
#define F_BINS   1025
#define OUT_LEN  511488
#define FPB      8                         // frames per block
#define BPB      125                       // blocks per batch (125*8 = 1000)
#define OAF      5632                      // OA window floats: 8*512 + 1536

#define P(a) ((a) + ((a) >> 4))            // LDS pad (complex units)

__device__ __forceinline__ void cmul(float ar, float ai, float br, float bi,
                                     float& cr, float& ci) {
    cr = ar * br - ai * bi;
    ci = ar * bi + ai * br;
}

__global__ __launch_bounds__(256) void istft_oa_kernel(const float* __restrict__ re,
                                                       const float* __restrict__ im,
                                                       const float* __restrict__ win,
                                                       float* __restrict__ scratch,
                                                       float* __restrict__ out) {
    __shared__ __align__(16) float2 buf[1088];     // P(1023)=1086
    __shared__ __align__(16) float2 oa2[OAF / 2];  // 2816 float2 = 5632 floats

    const int j   = blockIdx.x;            // block within batch
    const int b   = blockIdx.y;
    const int tid = threadIdx.x;
    const int t0  = j * FPB;

    // ---- zero the OA window (first OA add is 2 barriers away) ----
    {
        float4* z4 = (float4*)oa2;         // 1408 float4
        #pragma unroll
        for (int e = 0; e < 6; ++e) {
            int idx = tid + 256 * e;
            if (idx < 1408) z4[idx] = make_float4(0.f, 0.f, 0.f, 0.f);
        }
    }

    const float Sc = 0.5f / 1024.f;
    const float2* w2v = (const float2*)win;

    for (int d = 0; d < FPB; ++d) {
        const int f = b * T_FRAMES + t0 + d;
        const float* fr = re + (size_t)f * F_BINS;
        const float* fi = im + (size_t)f * F_BINS;

        // ---- pack to Z, store base-4 digit-reversed ----
        #pragma unroll
        for (int k0 = 0; k0 < 1024; k0 += 256) {
            int k = k0 + tid;
            float ar = fr[k];
            float ai = (k == 0) ? 0.f : fi[k];          // Im F[0] dropped
            int mk = 1024 - k;
            float br = fr[mk];
            float bi = (mk == 1024) ? 0.f : fi[mk];     // Im F[1024] dropped
            float dr = ar - br, di = ai + bi;           // X[k] - conj(X[m-k])
            float ang = 3.14159265358979f * (float)k / 1024.f;
            float sn, cs;
            __sincosf(ang, &sn, &cs);
            float Zr = (ar + br - (cs * di + sn * dr)) * Sc;
            float Zi = (ai - bi + (cs * dr - sn * di)) * Sc;
            unsigned r10 = __brev((unsigned)k) >> 22;                       // 10b rev
            int rk = (int)(((r10 & 0x155u) << 1) | ((r10 >> 1) & 0x155u)); // digit-rev
            buf[P(rk)] = make_float2(Zr, Zi);
        }
        __syncthreads();   // digit-reversal scatter is cross-wave

        // ---- stage 0 (hm=1): twiddles == 1, in-place ----
        {
            int base = tid << 2;
            int i0 = P(base), i1 = P(base + 1), i2 = P(base + 2), i3 = P(base + 3);
            float2 a = buf[i0], bb = buf[i1], c = buf[i2], dd = buf[i3];
            float t0r = a.x + c.x,  t0i = a.y + c.y;
            float t1r = a.x - c.x,  t1i = a.y - c.y;
            float t2r = bb.x + dd.x, t2i = bb.y + dd.y;
            float t3r = bb.x - dd.x, t3i = bb.y - dd.y;
            buf[i0] = make_float2(t0r + t2r, t0i + t2i);
            buf[i1] = make_float2(t1r - t3i, t1i + t3r);   // + i*t3
            buf[i2] = make_float2(t0r - t2r, t0i - t2i);
            buf[i3] = make_float2(t1r + t3i, t1i - t3r);   // - i*t3
        }

        // ---- stages 1..3: wave-local (waves own disjoint 256-elem regions) ----
        #pragma unroll
        for (int s = 1; s < 4; ++s) {
            __builtin_amdgcn_wave_barrier();
            const int hm = 1 << (2 * s);
            const int jj   = tid & (hm - 1);
            const int base = ((tid - jj) << 2) + jj;
            float ang = 1.57079632679f * (float)jj / (float)hm;   // 2π j/(4hm)
            float s1, c1;
            __sincosf(ang, &s1, &c1);                  // w1 = e^{+i ang}
            float c2, s2, c3, s3;
            cmul(c1, s1, c1, s1, c2, s2);              // w2 = w1^2
            cmul(c2, s2, c1, s1, c3, s3);              // w3 = w1^3

            int i0 = P(base), i1 = P(base + hm), i2 = P(base + 2 * hm), i3 = P(base + 3 * hm);
            float2 a = buf[i0], bb = buf[i1], c = buf[i2], dd = buf[i3];
            float br_, bi_, cr_, ci_, dr_, di_;
            cmul(bb.x, bb.y, c1, s1, br_, bi_);
            cmul(c.x,  c.y,  c2, s2, cr_, ci_);
            cmul(dd.x, dd.y, c3, s3, dr_, di_);

            float t0r = a.x + cr_, t0i = a.y + ci_;
            float t1r = a.x - cr_, t1i = a.y - ci_;
            float t2r = br_ + dr_, t2i = bi_ + di_;
            float t3r = br_ - dr_, t3i = bi_ - di_;
            buf[i0] = make_float2(t0r + t2r, t0i + t2i);
            buf[i1] = make_float2(t1r - t3i, t1i + t3r);
            buf[i2] = make_float2(t0r - t2r, t0i - t2i);
            buf[i3] = make_float2(t1r + t3i, t1i - t3r);
        }
        __syncthreads();   // stage 4 spans all 1024 points: cross-wave

        // ---- stage 4 (hm=256) fused with window + OA accumulate ----
        {
            float ang = 1.57079632679f * (float)tid / 256.f;
            float s1, c1;
            __sincosf(ang, &s1, &c1);
            float c2, s2, c3, s3;
            cmul(c1, s1, c1, s1, c2, s2);
            cmul(c2, s2, c1, s1, c3, s3);

            int i0 = P(tid), i1 = P(tid + 256), i2 = P(tid + 512), i3 = P(tid + 768);
            float2 a = buf[i0], bb = buf[i1], c = buf[i2], dd = buf[i3];
            float br_, bi_, cr_, ci_, dr_, di_;
            cmul(bb.x, bb.y, c1, s1, br_, bi_);
            cmul(c.x,  c.y,  c2, s2, cr_, ci_);
            cmul(dd.x, dd.y, c3, s3, dr_, di_);

            float t0r = a.x + cr_, t0i = a.y + ci_;
            float t1r = a.x - cr_, t1i = a.y - ci_;
            float t2r = br_ + dr_, t2i = bi_ + di_;
            float t3r = br_ - dr_, t3i = bi_ - di_;

            float2 z0 = make_float2(t0r + t2r, t0i + t2i);
            float2 z1 = make_float2(t1r - t3i, t1i + t3r);
            float2 z2 = make_float2(t0r - t2r, t0i - t2i);
            float2 z3 = make_float2(t1r + t3i, t1i - t3r);

            float2 w0 = w2v[tid],       w1 = w2v[tid + 256];
            float2 w2 = w2v[tid + 512], w3 = w2v[tid + 768];

            const int base2 = 256 * d;          // float2 index of 512*d
            float2 v;
            v = oa2[base2 + tid];
            v.x += z0.x * w0.x;  v.y += z0.y * w0.y;
            oa2[base2 + tid] = v;
            v = oa2[base2 + tid + 256];
            v.x += z1.x * w1.x;  v.y += z1.y * w1.y;
            oa2[base2 + tid + 256] = v;
            v = oa2[base2 + tid + 512];
            v.x += z2.x * w2.x;  v.y += z2.y * w2.y;
            oa2[base2 + tid + 512] = v;
            v = oa2[base2 + tid + 768];
            v.x += z3.x * w3.x;  v.y += z3.y * w3.y;
            oa2[base2 + tid + 768] = v;
        }
        __syncthreads();   // order OA adds vs next frame; buf free for next pack
    }

    // ---- complete region: floats [1536, 4096) -> out, wss == 1.5 exact ----
    const float inv = 2.f / 3.f;
    const float4* oa4 = (const float4*)oa2;
    float4* o4 = (float4*)(out + (size_t)b * OUT_LEN + (size_t)4096 * j + 512);
    #pragma unroll
    for (int e = 0; e < 3; ++e) {                  // 640 float4
        int idx = tid + 256 * e;
        if (idx < 640) {
            float4 v = oa4[384 + idx];
            o4[idx] = make_float4(v.x * inv, v.y * inv, v.z * inv, v.w * inv);
        }
    }
    // ---- seams: lead floats [0,1536) , trail floats [4096,5632) -> scratch ----
    float4* sc4 = (float4*)(scratch + (((size_t)b * BPB + j) * 2) * 1536);
    #pragma unroll
    for (int e = 0; e < 3; ++e) {                  // 768 float4: 0..383 lead, 384..767 trail
        int idx = tid + 256 * e;
        float4 v = (idx < 384) ? oa4[idx] : oa4[640 + idx];   // trail f4 base = 1024
        sc4[idx] = v;
    }
}

// Seam g of batch b covers n in [4096g, 4096g+1536); sum the trailing partial
// of block g-1 and the leading partial of block g. wss == 1.5 for
// n in [1536, 512000); generic gather wss at the global edges.
__global__ __launch_bounds__(256) void seam_kernel(const float* __restrict__ scratch,
                                                   const float* __restrict__ win,
                                                   float* __restrict__ out) {
    const int g = blockIdx.x;                      // 0..125
    const int b = blockIdx.y;

    #pragma unroll
    for (int e = 0; e < 6; ++e) {                  // 1536 = 6*256
        int i = threadIdx.x + 256 * e;
        int n = 4096 * g + i;
        int m = n - 1024;
        if (m < 0 || m >= OUT_LEN) continue;
        float s = 0.f;
        if (g > 0)
            s += scratch[(((size_t)b * BPB + (g - 1)) * 2 + 1) * 1536 + i];
        if (g < BPB)
            s += scratch[(((size_t)b * BPB + g) * 2) * 1536 + i];
        float r;
        if (n >= 1536 && n < 512000) {
            r = s * (2.f / 3.f);
        } else {
            int thi = n >> 9; if (thi > T_FRAMES - 1) thi = T_FRAMES - 1;
            int tlo = (n - (N_FFT - HOP)) >> 9; if (tlo < 0) tlo = 0;
            float wss = 0.f;
            for (int t = tlo; t <= thi; ++t) {
                float w = win[n - (t << 9)];
                wss += w * w;
            }
            r = (wss > 1.17549435e-38f) ? s / wss : s;
        }
        out[(size_t)b * OUT_LEN + m] = r;
    }
}

extern "C" void kernel_launch(void* const* d_in, const int* in_sizes, int n_in,
                              void* d_out, int out_size, void* d_ws, size_t ws_size,
                              hipStream_t stream) {
    const float* re  = (const float*)d_in[0];
    const float* im  = (const float*)d_in[1];
    // d_in[2], d_in[3] (W_real, W_imag) unused: the FFT computes their action.
    const float* win = (const float*)d_in[4];
    float* out = (float*)d_out;

    float* scratch = (float*)d_ws;   // 8 * 125 * 2 * 1536 * 4 B = 12,288,000 B

    istft_oa_kernel<<<dim3(BPB, 8), 256, 0, stream>>>(re, im, win, scratch, out);
    seam_kernel<<<dim3(BPB + 1, 8), 256, 0, stream>>>(scratch, win, out);
}